// Round 2
// baseline (62.606 us; speedup 1.0000x reference)
//
#include <hip/hip_runtime.h>

static constexpr int B  = 32;
static constexpr int Q  = 900;   // queries (and pseudo targets Qb)
static constexpr int NC = 91;    // classes
static constexpr int T  = 30;    // gt targets
static constexpr int QT = 36;    // q-rows per block in cost kernel (900 = 25*36)

static constexpr float ALPHA_  = 0.25f;
static constexpr float EPS_    = 1e-8f;
static constexpr float W_CLASS = 2.0f;
static constexpr float W_BBOX  = 5.0f;
static constexpr float W_GIOU  = 2.0f;
static constexpr float BIG_    = 1e9f;

// ---------------------------------------------------------------------------
// K1: per (b, qb) of the base model: argmax label, pseudo mask.
// Mask is correctness-critical (flip => 1e9-scale error). Exact IEEE fp32,
// no contraction, same op order as the reference.
// ---------------------------------------------------------------------------
__global__ void k1_mask_label(const float* __restrict__ logits_base,
                              const float4* __restrict__ boxes_base,
                              const float4* __restrict__ targets,
                              int* __restrict__ labels,
                              float* __restrict__ mask_out) {
#pragma clang fp contract(off)
  int idx = blockIdx.x * blockDim.x + threadIdx.x;
  if (idx >= B * Q) return;
  int b = idx / Q;

  // argmax over 91 logits (sigmoid is monotone; first-max semantics match)
  const float* row = logits_base + (size_t)idx * NC;
  float m = row[0];
  int arg = 0;
  for (int c = 1; c < NC; ++c) {
    float v = row[c];
    if (v > m) { m = v; arg = c; }
  }
  bool keep = (m > 0.0f);  // sigmoid(m) > 0.5  <=>  m > 0

  // base box -> xyxy (exact reference op order)
  float4 bb = boxes_base[idx];
  float x1 = bb.x - 0.5f * bb.z, y1 = bb.y - 0.5f * bb.w;
  float x2 = bb.x + 0.5f * bb.z, y2 = bb.y + 0.5f * bb.w;
  float a1 = (x2 - x1) * (y2 - y1);

  const float4* tg = targets + (size_t)b * T;
  for (int t = 0; t < T; ++t) {
    float4 tb = tg[t];
    float tx1 = tb.x - 0.5f * tb.z, ty1 = tb.y - 0.5f * tb.w;
    float tx2 = tb.x + 0.5f * tb.z, ty2 = tb.y + 0.5f * tb.w;
    float a2 = (tx2 - tx1) * (ty2 - ty1);
    float ltx = fmaxf(x1, tx1), lty = fmaxf(y1, ty1);
    float rbx = fminf(x2, tx2), rby = fminf(y2, ty2);
    float iw = fmaxf(rbx - ltx, 0.0f), ih = fmaxf(rby - lty, 0.0f);
    float inter = iw * ih;
    float uni = (a1 + a2) - inter;         // reference grouping
    float iou = inter / uni;               // IEEE divide
    float cx1 = fminf(x1, tx1), cy1 = fminf(y1, ty1);
    float cx2 = fmaxf(x2, tx2), cy2 = fmaxf(y2, ty2);
    float cw = fmaxf(cx2 - cx1, 0.0f), ch = fmaxf(cy2 - cy1, 0.0f);
    float ac = cw * ch;
    float g = iou - (ac - uni) / ac;
    keep = keep && (-g > -0.1f);           // reference: all(-g > bbox_thresh)
  }

  labels[idx] = arg;
  mask_out[idx] = keep ? 1.0f : 0.0f;
}

// focal-style class cost for one logit (tolerance 2e7: fast intrinsics fine)
__device__ __forceinline__ float class_cost(float x) {
  float p   = __builtin_amdgcn_rcpf(1.0f + __expf(-x));
  float omp = 1.0f - p;
  float pos = ALPHA_ * (omp * omp) * (-__logf(p + EPS_));
  float neg = (1.0f - ALPHA_) * (p * p) * (-__logf(omp + EPS_));
  return pos - neg;
}

// ---------------------------------------------------------------------------
// K3: cost matrix. Block = (b, 36 q-rows) x all 900 qb.
// Thread owns 4 qb columns in registers; class-cost tile staged in LDS
// (computed from logits during staging -- fuses the elementwise pass).
// ---------------------------------------------------------------------------
__global__ __launch_bounds__(256) void k3_cost(
    const float* __restrict__ pred_logits,
    const float4* __restrict__ pred_boxes,
    const float4* __restrict__ boxes_base,
    const int* __restrict__ labels,
    const float* __restrict__ mask_in,
    float* __restrict__ Cout) {
  __shared__ float  s_cc[QT * NC];  // 36*91 floats = 13.1 KB
  __shared__ float4 s_pb[QT];

  int b  = blockIdx.x / (Q / QT);
  int q0 = (blockIdx.x % (Q / QT)) * QT;
  int tid = threadIdx.x;

  // stage class costs for this q tile (contiguous 3276 floats)
  const float* lg = pred_logits + ((size_t)(b * Q + q0)) * NC;
  for (int i = tid; i < QT * NC; i += 256) s_cc[i] = class_cost(lg[i]);
  if (tid < QT) s_pb[tid] = pred_boxes[b * Q + q0 + tid];

  // per-thread qb-side state (4 columns each)
  float cxb[4], cyb[4], wbx[4], hbx[4], x1b[4], y1b[4], x2b[4], y2b[4], ab[4];
  int lb[4];
  bool mk[4];
#pragma unroll
  for (int k = 0; k < 4; ++k) {
    int qb = tid + 256 * k;
    mk[k] = false; lb[k] = 0;
    cxb[k] = cyb[k] = wbx[k] = hbx[k] = 0.0f;
    x1b[k] = y1b[k] = x2b[k] = y2b[k] = ab[k] = 0.0f;
    if (qb < Q) {
      int j = b * Q + qb;
      float4 bb = boxes_base[j];
      cxb[k] = bb.x; cyb[k] = bb.y; wbx[k] = bb.z; hbx[k] = bb.w;
      x1b[k] = bb.x - 0.5f * bb.z; y1b[k] = bb.y - 0.5f * bb.w;
      x2b[k] = bb.x + 0.5f * bb.z; y2b[k] = bb.y + 0.5f * bb.w;
      ab[k]  = (x2b[k] - x1b[k]) * (y2b[k] - y1b[k]);
      lb[k]  = labels[j];
      mk[k]  = (mask_in[j] != 0.0f);
    }
  }
  __syncthreads();

  for (int qi = 0; qi < QT; ++qi) {
    float4 pb = s_pb[qi];
    float px1 = pb.x - 0.5f * pb.z, py1 = pb.y - 0.5f * pb.w;
    float px2 = pb.x + 0.5f * pb.z, py2 = pb.y + 0.5f * pb.w;
    float pa  = (px2 - px1) * (py2 - py1);
    float* crow = Cout + ((size_t)(b * Q + q0 + qi)) * Q;
    const float* ccq = s_cc + qi * NC;
#pragma unroll
    for (int k = 0; k < 4; ++k) {
      int qb = tid + 256 * k;
      if (qb < Q) {
        float cls = ccq[lb[k]];  // LDS gather, ~2 lanes/bank (free)
        float l1 = fabsf(pb.x - cxb[k]) + fabsf(pb.y - cyb[k]) +
                   fabsf(pb.z - wbx[k]) + fabsf(pb.w - hbx[k]);
        float ltx = fmaxf(px1, x1b[k]), lty = fmaxf(py1, y1b[k]);
        float rbx = fminf(px2, x2b[k]), rby = fminf(py2, y2b[k]);
        float iw = fmaxf(rbx - ltx, 0.0f), ih = fmaxf(rby - lty, 0.0f);
        float inter = iw * ih;
        float uni = (pa + ab[k]) - inter;
        float iou = inter * __builtin_amdgcn_rcpf(uni);
        float c1x = fminf(px1, x1b[k]), c1y = fminf(py1, y1b[k]);
        float c2x = fmaxf(px2, x2b[k]), c2y = fmaxf(py2, y2b[k]);
        float cw = fmaxf(c2x - c1x, 0.0f), ch = fmaxf(c2y - c1y, 0.0f);
        float acl = cw * ch;
        float g = iou - (acl - uni) * __builtin_amdgcn_rcpf(acl);
        float cost = W_BBOX * l1 + W_CLASS * cls - W_GIOU * g;
        crow[qb] = mk[k] ? cost : BIG_;
      }
    }
  }
}

extern "C" void kernel_launch(void* const* d_in, const int* in_sizes, int n_in,
                              void* d_out, int out_size, void* d_ws, size_t ws_size,
                              hipStream_t stream) {
  const float*  pred_logits      = (const float*)d_in[0];
  const float4* pred_boxes       = (const float4*)d_in[1];
  const float*  pred_logits_base = (const float*)d_in[2];
  const float4* pred_boxes_base  = (const float4*)d_in[3];
  const float4* targets          = (const float4*)d_in[4];

  float* out      = (float*)d_out;
  float* mask_out = out + (size_t)B * Q * Q;  // output 1, after C

  int* labels = (int*)d_ws;  // 28800 ints

  k1_mask_label<<<(B * Q + 255) / 256, 256, 0, stream>>>(
      pred_logits_base, pred_boxes_base, targets, labels, mask_out);

  k3_cost<<<B * (Q / QT), 256, 0, stream>>>(
      pred_logits, pred_boxes, pred_boxes_base, labels, mask_out, out);
}

// Round 3
// 54.335 us; speedup vs baseline: 1.1522x; 1.1522x over previous
//
#include <hip/hip_runtime.h>

static constexpr int B  = 32;
static constexpr int Q  = 900;   // queries (and pseudo targets Qb)
static constexpr int NC = 91;    // classes
static constexpr int T  = 30;    // gt targets
static constexpr int QT = 18;    // q-rows per block in cost kernel (900 = 50*18)

static constexpr float ALPHA_  = 0.25f;
static constexpr float EPS_    = 1e-8f;
static constexpr float W_CLASS = 2.0f;
static constexpr float W_BBOX  = 5.0f;
static constexpr float W_GIOU  = 2.0f;
static constexpr float BIG_    = 1e9f;

// ---------------------------------------------------------------------------
// K1: wave-cooperative. One 64-lane wave per (b, qb) of the base model:
// coalesced logit read + butterfly argmax; one gt target per lane for the
// keep-mask. Mask is correctness-critical: exact IEEE fp32, no contraction,
// same op order as the reference.
// ---------------------------------------------------------------------------
__global__ __launch_bounds__(256) void k1_mask_label(
    const float* __restrict__ logits_base,
    const float4* __restrict__ boxes_base,
    const float4* __restrict__ targets,
    int* __restrict__ labels,
    float* __restrict__ mask_out) {
#pragma clang fp contract(off)
  int wid  = (blockIdx.x * blockDim.x + threadIdx.x) >> 6;  // global wave id
  int lane = threadIdx.x & 63;
  if (wid >= B * Q) return;
  int b = wid / Q;

  // ---- argmax over 91 logits (first-max; ties only perturb class cost) ----
  const float* row = logits_base + (size_t)wid * NC;
  float v  = (lane < NC) ? row[lane] : -1e30f;
  int  arg = lane;
  int lane2 = lane + 64;
  if (lane2 < NC) {
    float v2 = row[lane2];
    if (v2 > v) { v = v2; arg = lane2; }   // strict >: keep lower idx on tie
  }
  for (int off = 32; off >= 1; off >>= 1) {
    float ov = __shfl_xor(v, off, 64);
    int   oi = __shfl_xor(arg, off, 64);
    if (ov > v || (ov == v && oi < arg)) { v = ov; arg = oi; }
  }
  bool keep = (v > 0.0f);  // sigmoid(max) > 0.5  <=>  max logit > 0

  // ---- keep-mask: one target per lane, exact reference arithmetic ----
  float4 bb = boxes_base[wid];               // broadcast load
  float x1 = bb.x - 0.5f * bb.z, y1 = bb.y - 0.5f * bb.w;
  float x2 = bb.x + 0.5f * bb.z, y2 = bb.y + 0.5f * bb.w;
  float a1 = (x2 - x1) * (y2 - y1);

  bool ok = true;
  if (lane < T) {
    float4 tb = targets[b * T + lane];
    float tx1 = tb.x - 0.5f * tb.z, ty1 = tb.y - 0.5f * tb.w;
    float tx2 = tb.x + 0.5f * tb.z, ty2 = tb.y + 0.5f * tb.w;
    float a2 = (tx2 - tx1) * (ty2 - ty1);
    float ltx = fmaxf(x1, tx1), lty = fmaxf(y1, ty1);
    float rbx = fminf(x2, tx2), rby = fminf(y2, ty2);
    float iw = fmaxf(rbx - ltx, 0.0f), ih = fmaxf(rby - lty, 0.0f);
    float inter = iw * ih;
    float uni = (a1 + a2) - inter;           // reference grouping
    float iou = inter / uni;                 // IEEE divide
    float cx1 = fminf(x1, tx1), cy1 = fminf(y1, ty1);
    float cx2 = fmaxf(x2, tx2), cy2 = fmaxf(y2, ty2);
    float cw = fmaxf(cx2 - cx1, 0.0f), ch = fmaxf(cy2 - cy1, 0.0f);
    float ac = cw * ch;
    float g = iou - (ac - uni) / ac;
    ok = (-g > -0.1f);                       // reference: all(-g > bbox_thresh)
  }
  keep = keep && __all(ok);

  if (lane == 0) {
    labels[wid]   = arg;
    mask_out[wid] = keep ? 1.0f : 0.0f;
  }
}

// focal-style class cost for one logit (tolerance 2e7: fast intrinsics fine)
__device__ __forceinline__ float class_cost(float x) {
  float p   = __builtin_amdgcn_rcpf(1.0f + __expf(-x));
  float omp = 1.0f - p;
  float pos = ALPHA_ * (omp * omp) * (-__logf(p + EPS_));
  float neg = (1.0f - ALPHA_) * (p * p) * (-__logf(omp + EPS_));
  return pos - neg;
}

// ---------------------------------------------------------------------------
// K3: cost matrix. Block = (b, 18 q-rows) x all 900 qb. Thread t<225 owns 4
// CONSECUTIVE qb -> one float4 store per row. Class-cost tile + per-row
// derived box values staged in LDS once per block.
// ---------------------------------------------------------------------------
__global__ __launch_bounds__(256) void k3_cost(
    const float* __restrict__ pred_logits,
    const float4* __restrict__ pred_boxes,
    const float4* __restrict__ boxes_base,
    const int* __restrict__ labels,
    const float* __restrict__ mask_in,
    float* __restrict__ Cout) {
  __shared__ float s_cc[QT * NC];    // 18*91 = 1638 floats (6.4 KB)
  __shared__ float s_row[QT][12];    // cx,cy,w,h, x1,y1,x2,y2, area

  int b   = blockIdx.x / (Q / QT);
  int q0  = (blockIdx.x % (Q / QT)) * QT;
  int tid = threadIdx.x;

  // stage class costs for this q tile (contiguous floats, coalesced)
  const float* lg = pred_logits + ((size_t)(b * Q + q0)) * NC;
  for (int i = tid; i < QT * NC; i += 256) s_cc[i] = class_cost(lg[i]);

  // stage per-row derived values (once per block, not per thread)
  if (tid < QT) {
    float4 pb = pred_boxes[b * Q + q0 + tid];
    float px1 = pb.x - 0.5f * pb.z, py1 = pb.y - 0.5f * pb.w;
    float px2 = pb.x + 0.5f * pb.z, py2 = pb.y + 0.5f * pb.w;
    s_row[tid][0] = pb.x; s_row[tid][1] = pb.y;
    s_row[tid][2] = pb.z; s_row[tid][3] = pb.w;
    s_row[tid][4] = px1;  s_row[tid][5] = py1;
    s_row[tid][6] = px2;  s_row[tid][7] = py2;
    s_row[tid][8] = (px2 - px1) * (py2 - py1);
  }

  // per-thread qb-side state: 4 consecutive columns
  bool active = (tid < Q / 4);  // 225
  float cxb[4], cyb[4], wbx[4], hbx[4], x1b[4], y1b[4], x2b[4], y2b[4], ab[4];
  int lb[4];
  bool mk[4];
  int jbase = b * Q + 4 * tid;
  if (active) {
    int4 lbv = *reinterpret_cast<const int4*>(labels + jbase);
    float4 mkv = *reinterpret_cast<const float4*>(mask_in + jbase);
    lb[0] = lbv.x; lb[1] = lbv.y; lb[2] = lbv.z; lb[3] = lbv.w;
    mk[0] = mkv.x != 0.0f; mk[1] = mkv.y != 0.0f;
    mk[2] = mkv.z != 0.0f; mk[3] = mkv.w != 0.0f;
#pragma unroll
    for (int k = 0; k < 4; ++k) {
      float4 bb = boxes_base[jbase + k];
      cxb[k] = bb.x; cyb[k] = bb.y; wbx[k] = bb.z; hbx[k] = bb.w;
      x1b[k] = bb.x - 0.5f * bb.z; y1b[k] = bb.y - 0.5f * bb.w;
      x2b[k] = bb.x + 0.5f * bb.z; y2b[k] = bb.y + 0.5f * bb.w;
      ab[k]  = (x2b[k] - x1b[k]) * (y2b[k] - y1b[k]);
    }
  }
  __syncthreads();

  if (active) {
    size_t rowbase = ((size_t)(b * Q + q0)) * Q;
    for (int qi = 0; qi < QT; ++qi, rowbase += Q) {
      float pcx = s_row[qi][0], pcy = s_row[qi][1];
      float pw  = s_row[qi][2], ph  = s_row[qi][3];
      float px1 = s_row[qi][4], py1 = s_row[qi][5];
      float px2 = s_row[qi][6], py2 = s_row[qi][7];
      float pa  = s_row[qi][8];
      const float* ccq = s_cc + qi * NC;
      float res[4];
#pragma unroll
      for (int k = 0; k < 4; ++k) {
        float cls = ccq[lb[k]];  // LDS gather within 364B window
        float l1 = fabsf(pcx - cxb[k]) + fabsf(pcy - cyb[k]) +
                   fabsf(pw - wbx[k]) + fabsf(ph - hbx[k]);
        float ltx = fmaxf(px1, x1b[k]), lty = fmaxf(py1, y1b[k]);
        float rbx = fminf(px2, x2b[k]), rby = fminf(py2, y2b[k]);
        float iw = fmaxf(rbx - ltx, 0.0f), ih = fmaxf(rby - lty, 0.0f);
        float inter = iw * ih;
        float uni = (pa + ab[k]) - inter;
        float iou = inter * __builtin_amdgcn_rcpf(uni);
        float c1x = fminf(px1, x1b[k]), c1y = fminf(py1, y1b[k]);
        float c2x = fmaxf(px2, x2b[k]), c2y = fmaxf(py2, y2b[k]);
        float cw = fmaxf(c2x - c1x, 0.0f), ch = fmaxf(c2y - c1y, 0.0f);
        float acl = cw * ch;
        float g = iou - (acl - uni) * __builtin_amdgcn_rcpf(acl);
        float cost = W_BBOX * l1 + W_CLASS * cls - W_GIOU * g;
        res[k] = mk[k] ? cost : BIG_;
      }
      float4 out4 = make_float4(res[0], res[1], res[2], res[3]);
      *reinterpret_cast<float4*>(Cout + rowbase + 4 * tid) = out4;
    }
  }
}

extern "C" void kernel_launch(void* const* d_in, const int* in_sizes, int n_in,
                              void* d_out, int out_size, void* d_ws, size_t ws_size,
                              hipStream_t stream) {
  const float*  pred_logits      = (const float*)d_in[0];
  const float4* pred_boxes       = (const float4*)d_in[1];
  const float*  pred_logits_base = (const float*)d_in[2];
  const float4* pred_boxes_base  = (const float4*)d_in[3];
  const float4* targets          = (const float4*)d_in[4];

  float* out      = (float*)d_out;
  float* mask_out = out + (size_t)B * Q * Q;  // output 1, after C

  int* labels = (int*)d_ws;  // 28800 ints

  // one wave per (b, qb): 28800 waves * 64 lanes / 256 = 7200 blocks
  k1_mask_label<<<(B * Q * 64) / 256, 256, 0, stream>>>(
      pred_logits_base, pred_boxes_base, targets, labels, mask_out);

  k3_cost<<<B * (Q / QT), 256, 0, stream>>>(
      pred_logits, pred_boxes, pred_boxes_base, labels, mask_out, out);
}

// Round 4
// 49.857 us; speedup vs baseline: 1.2557x; 1.0898x over previous
//
#include <hip/hip_runtime.h>

static constexpr int B  = 32;
static constexpr int Q  = 900;   // queries (and pseudo targets Qb)
static constexpr int NC = 91;    // classes
static constexpr int T  = 30;    // gt targets
static constexpr int QT = 12;    // q-rows per block in cost kernel (900 = 75*12)

static constexpr float ALPHA_  = 0.25f;
static constexpr float EPS_    = 1e-8f;
static constexpr float BIG_    = 1e9f;

// ---------------------------------------------------------------------------
// K1: wave-cooperative. One 64-lane wave per (b, qb) of the base model:
// coalesced logit read + butterfly argmax; one gt target per lane for the
// keep-mask. Mask is correctness-critical: exact IEEE fp32, no contraction,
// same op order as the reference.
// ---------------------------------------------------------------------------
__global__ __launch_bounds__(256) void k1_mask_label(
    const float* __restrict__ logits_base,
    const float4* __restrict__ boxes_base,
    const float4* __restrict__ targets,
    int* __restrict__ labels,
    float* __restrict__ mask_out) {
#pragma clang fp contract(off)
  int wid  = (blockIdx.x * blockDim.x + threadIdx.x) >> 6;  // global wave id
  int lane = threadIdx.x & 63;
  if (wid >= B * Q) return;
  int b = wid / Q;

  // ---- argmax over 91 logits (first-max; ties only perturb class cost) ----
  const float* row = logits_base + (size_t)wid * NC;
  float v  = (lane < NC) ? row[lane] : -1e30f;
  int  arg = lane;
  int lane2 = lane + 64;
  if (lane2 < NC) {
    float v2 = row[lane2];
    if (v2 > v) { v = v2; arg = lane2; }   // strict >: keep lower idx on tie
  }
  for (int off = 32; off >= 1; off >>= 1) {
    float ov = __shfl_xor(v, off, 64);
    int   oi = __shfl_xor(arg, off, 64);
    if (ov > v || (ov == v && oi < arg)) { v = ov; arg = oi; }
  }
  bool keep = (v > 0.0f);  // sigmoid(max) > 0.5  <=>  max logit > 0

  // ---- keep-mask: one target per lane, exact reference arithmetic ----
  float4 bb = boxes_base[wid];               // broadcast load
  float x1 = bb.x - 0.5f * bb.z, y1 = bb.y - 0.5f * bb.w;
  float x2 = bb.x + 0.5f * bb.z, y2 = bb.y + 0.5f * bb.w;
  float a1 = (x2 - x1) * (y2 - y1);

  bool ok = true;
  if (lane < T) {
    float4 tb = targets[b * T + lane];
    float tx1 = tb.x - 0.5f * tb.z, ty1 = tb.y - 0.5f * tb.w;
    float tx2 = tb.x + 0.5f * tb.z, ty2 = tb.y + 0.5f * tb.w;
    float a2 = (tx2 - tx1) * (ty2 - ty1);
    float ltx = fmaxf(x1, tx1), lty = fmaxf(y1, ty1);
    float rbx = fminf(x2, tx2), rby = fminf(y2, ty2);
    float iw = fmaxf(rbx - ltx, 0.0f), ih = fmaxf(rby - lty, 0.0f);
    float inter = iw * ih;
    float uni = (a1 + a2) - inter;           // reference grouping
    float iou = inter / uni;                 // IEEE divide
    float cx1 = fminf(x1, tx1), cy1 = fminf(y1, ty1);
    float cx2 = fmaxf(x2, tx2), cy2 = fmaxf(y2, ty2);
    float cw = fmaxf(cx2 - cx1, 0.0f), ch = fmaxf(cy2 - cy1, 0.0f);
    float ac = cw * ch;
    float g = iou - (ac - uni) / ac;
    ok = (-g > -0.1f);                       // reference: all(-g > bbox_thresh)
  }
  keep = keep && __all(ok);

  if (lane == 0) {
    labels[wid]   = arg;
    mask_out[wid] = keep ? 1.0f : 0.0f;
  }
}

// focal-style class cost for one logit (tolerance 2e7: fast intrinsics fine)
__device__ __forceinline__ float class_cost(float x) {
  float p   = __builtin_amdgcn_rcpf(1.0f + __expf(-x));
  float omp = 1.0f - p;
  float pos = ALPHA_ * (omp * omp) * (-__logf(p + EPS_));
  float neg = (1.0f - ALPHA_) * (p * p) * (-__logf(omp + EPS_));
  return pos - neg;
}

// ---------------------------------------------------------------------------
// K2: elementwise class cost over all current-model logits (float4 stream).
// Runs at full device parallelism so k3's prologue has no transcendentals.
// ---------------------------------------------------------------------------
__global__ __launch_bounds__(256) void k2_class_cost(
    const float4* __restrict__ lg, float4* __restrict__ cc, int n4) {
  int i = blockIdx.x * 256 + threadIdx.x;
  if (i < n4) {
    float4 v = lg[i];
    float4 o;
    o.x = class_cost(v.x);
    o.y = class_cost(v.y);
    o.z = class_cost(v.z);
    o.w = class_cost(v.w);
    cc[i] = o;
  }
}

// ---------------------------------------------------------------------------
// K3: cost matrix. Block = (b, 12 q-rows) x all 900 qb. Thread t<225 owns 4
// consecutive qb -> one float4 store per row. Precomputed class costs copied
// to LDS (trivial prologue); qi loop fully unrolled -> immediate-offset LDS
// reads. Algebraic giou: enclosing box from intersection terms, single rcp,
// BIG mask folded into a per-column constant.
// ---------------------------------------------------------------------------
__global__ __launch_bounds__(256) void k3_cost(
    const float* __restrict__ cc_all,
    const float4* __restrict__ pred_boxes,
    const float4* __restrict__ boxes_base,
    const int* __restrict__ labels,
    const float* __restrict__ mask_in,
    float* __restrict__ Cout) {
  __shared__ float  s_cc[QT * NC];   // 12*91 = 1092 floats (4.4 KB)
  __shared__ float4 s_row[QT][2];    // [0]=cx,cy,w,h  [1]=x1,y1,x2,y2
  __shared__ float  s_pa[QT];        // row area

  int b   = blockIdx.x / (Q / QT);
  int q0  = (blockIdx.x % (Q / QT)) * QT;
  int tid = threadIdx.x;

  // stage class costs: plain vector copy (1092 floats = 273 float4, aligned)
  const float4* ccs = reinterpret_cast<const float4*>(
      cc_all + ((size_t)(b * Q + q0)) * NC);
  float4* sc4 = reinterpret_cast<float4*>(s_cc);
  for (int i = tid; i < QT * NC / 4; i += 256) sc4[i] = ccs[i];

  if (tid < QT) {
    float4 pb = pred_boxes[b * Q + q0 + tid];
    float px1 = pb.x - 0.5f * pb.z, py1 = pb.y - 0.5f * pb.w;
    float px2 = pb.x + 0.5f * pb.z, py2 = pb.y + 0.5f * pb.w;
    s_row[tid][0] = pb;
    s_row[tid][1] = make_float4(px1, py1, px2, py2);
    s_pa[tid] = (px2 - px1) * (py2 - py1);
  }

  // per-thread qb-side state: 4 consecutive columns
  bool active = (tid < Q / 4);  // 225
  float cxb[4], cyb[4], wbx[4], hbx[4], x1b[4], y1b[4], x2b[4], y2b[4], ab[4];
  float c2big[4];
  int lb[4];
  int jbase = b * Q + 4 * tid;
  if (active) {
    int4 lbv = *reinterpret_cast<const int4*>(labels + jbase);
    float4 mkv = *reinterpret_cast<const float4*>(mask_in + jbase);
    lb[0] = lbv.x; lb[1] = lbv.y; lb[2] = lbv.z; lb[3] = lbv.w;
    c2big[0] = 2.0f + (mkv.x != 0.0f ? 0.0f : BIG_);
    c2big[1] = 2.0f + (mkv.y != 0.0f ? 0.0f : BIG_);
    c2big[2] = 2.0f + (mkv.z != 0.0f ? 0.0f : BIG_);
    c2big[3] = 2.0f + (mkv.w != 0.0f ? 0.0f : BIG_);
#pragma unroll
    for (int k = 0; k < 4; ++k) {
      float4 bb = boxes_base[jbase + k];
      cxb[k] = bb.x; cyb[k] = bb.y; wbx[k] = bb.z; hbx[k] = bb.w;
      x1b[k] = bb.x - 0.5f * bb.z; y1b[k] = bb.y - 0.5f * bb.w;
      x2b[k] = bb.x + 0.5f * bb.z; y2b[k] = bb.y + 0.5f * bb.w;
      ab[k]  = (x2b[k] - x1b[k]) * (y2b[k] - y1b[k]);
    }
  }
  __syncthreads();

  if (active) {
    size_t rowbase = ((size_t)(b * Q + q0)) * Q + 4 * tid;
#pragma unroll
    for (int qi = 0; qi < QT; ++qi, rowbase += Q) {
      float4 pc = s_row[qi][0];   // cx, cy, w, h
      float4 pe = s_row[qi][1];   // x1, y1, x2, y2
      float pa  = s_pa[qi];
      const float* ccq = s_cc + qi * NC;
      float res[4];
#pragma unroll
      for (int k = 0; k < 4; ++k) {
        float cls = ccq[lb[k]];  // ds_read, immediate qi offset
        float l1 = fabsf(pc.x - cxb[k]) + fabsf(pc.y - cyb[k]) +
                   fabsf(pc.z - wbx[k]) + fabsf(pc.w - hbx[k]);
        // intersection span (unclipped)
        float mwx = fminf(pe.z, x2b[k]) - fmaxf(pe.x, x1b[k]);
        float mwy = fminf(pe.w, y2b[k]) - fmaxf(pe.y, y1b[k]);
        float iw = fmaxf(mwx, 0.0f), ih = fmaxf(mwy, 0.0f);
        float inter = iw * ih;
        float uni = (pa + ab[k]) - inter;
        // enclosing box via identity: cw = (pw + wb) - mwx
        float cw = (pc.z + wbx[k]) - mwx;
        float ch = (pc.w + hbx[k]) - mwy;
        float acl = cw * ch;
        // t = iou + uni/acl = (inter*acl + uni^2) / (uni*acl); cost uses -2t
        float r = __builtin_amdgcn_rcpf(uni * acl);
        float t = (inter * acl + uni * uni) * r;
        res[k] = fmaf(-2.0f, t, fmaf(5.0f, l1, fmaf(2.0f, cls, c2big[k])));
      }
      *reinterpret_cast<float4*>(Cout + rowbase) =
          make_float4(res[0], res[1], res[2], res[3]);
    }
  }
}

extern "C" void kernel_launch(void* const* d_in, const int* in_sizes, int n_in,
                              void* d_out, int out_size, void* d_ws, size_t ws_size,
                              hipStream_t stream) {
  const float*  pred_logits      = (const float*)d_in[0];
  const float4* pred_boxes       = (const float4*)d_in[1];
  const float*  pred_logits_base = (const float*)d_in[2];
  const float4* pred_boxes_base  = (const float4*)d_in[3];
  const float4* targets          = (const float4*)d_in[4];

  float* out      = (float*)d_out;
  float* mask_out = out + (size_t)B * Q * Q;  // output 1, after C

  int*   labels = (int*)d_ws;                        // 28800 ints
  float* cc     = (float*)((char*)d_ws + 131072);    // 2.62M floats

  // one wave per (b, qb): 28800 waves * 64 lanes / 256 = 7200 blocks
  k1_mask_label<<<(B * Q * 64) / 256, 256, 0, stream>>>(
      pred_logits_base, pred_boxes_base, targets, labels, mask_out);

  int n4 = B * Q * NC / 4;  // 655200
  k2_class_cost<<<(n4 + 255) / 256, 256, 0, stream>>>(
      (const float4*)pred_logits, (float4*)cc, n4);

  k3_cost<<<B * (Q / QT), 256, 0, stream>>>(
      cc, pred_boxes, pred_boxes_base, labels, mask_out, out);
}

// Round 7
// 47.426 us; speedup vs baseline: 1.3201x; 1.0513x over previous
//
#include <hip/hip_runtime.h>

typedef float f32x4 __attribute__((ext_vector_type(4)));

static constexpr int B  = 32;
static constexpr int Q  = 900;   // queries (and pseudo targets Qb)
static constexpr int NC = 91;    // classes
static constexpr int T  = 30;    // gt targets
static constexpr int QT = 12;    // q-rows per block in cost kernel (900 = 75*12)

static constexpr float ALPHA_ = 0.25f;
static constexpr float EPS_   = 1e-8f;
static constexpr float BIG_   = 1e9f;

static constexpr int K1_BLOCKS = (B * Q) / 4;       // 7200 (4 waves/block)
static constexpr int N4        = B * Q * NC / 4;    // 655200 float4s of logits
static constexpr int K2_BLOCKS = (N4 + 255) / 256;  // 2560

// focal-style class cost for one logit (tolerance 2e7: fast intrinsics fine)
__device__ __forceinline__ float class_cost(float x) {
  float p   = __builtin_amdgcn_rcpf(1.0f + __expf(-x));
  float omp = 1.0f - p;
  float pos = ALPHA_ * (omp * omp) * (-__logf(p + EPS_));
  float neg = (1.0f - ALPHA_) * (p * p) * (-__logf(omp + EPS_));
  return pos - neg;
}

// ---------------------------------------------------------------------------
// K1 body: one 64-lane wave per (b, qb) of the base model. Coalesced logit
// read + butterfly argmax; one gt target per lane for the keep-mask.
// Mask is correctness-critical: exact IEEE fp32, no contraction, reference
// op order. (Unchanged from the passing round-4 version.)
// ---------------------------------------------------------------------------
__device__ void mask_label_body(int wid, int lane,
                                const float* __restrict__ logits_base,
                                const float4* __restrict__ boxes_base,
                                const float4* __restrict__ targets,
                                int* __restrict__ labels,
                                float* __restrict__ mask_out) {
#pragma clang fp contract(off)
  int b = wid / Q;

  const float* row = logits_base + (size_t)wid * NC;
  float v  = (lane < NC) ? row[lane] : -1e30f;
  int  arg = lane;
  int lane2 = lane + 64;
  if (lane2 < NC) {
    float v2 = row[lane2];
    if (v2 > v) { v = v2; arg = lane2; }   // strict >: keep lower idx on tie
  }
  for (int off = 32; off >= 1; off >>= 1) {
    float ov = __shfl_xor(v, off, 64);
    int   oi = __shfl_xor(arg, off, 64);
    if (ov > v || (ov == v && oi < arg)) { v = ov; arg = oi; }
  }
  bool keep = (v > 0.0f);  // sigmoid(max) > 0.5  <=>  max logit > 0

  float4 bb = boxes_base[wid];
  float x1 = bb.x - 0.5f * bb.z, y1 = bb.y - 0.5f * bb.w;
  float x2 = bb.x + 0.5f * bb.z, y2 = bb.y + 0.5f * bb.w;
  float a1 = (x2 - x1) * (y2 - y1);

  bool ok = true;
  if (lane < T) {
    float4 tb = targets[b * T + lane];
    float tx1 = tb.x - 0.5f * tb.z, ty1 = tb.y - 0.5f * tb.w;
    float tx2 = tb.x + 0.5f * tb.z, ty2 = tb.y + 0.5f * tb.w;
    float a2 = (tx2 - tx1) * (ty2 - ty1);
    float ltx = fmaxf(x1, tx1), lty = fmaxf(y1, ty1);
    float rbx = fminf(x2, tx2), rby = fminf(y2, ty2);
    float iw = fmaxf(rbx - ltx, 0.0f), ih = fmaxf(rby - lty, 0.0f);
    float inter = iw * ih;
    float uni = (a1 + a2) - inter;           // reference grouping
    float iou = inter / uni;                 // IEEE divide
    float cx1 = fminf(x1, tx1), cy1 = fminf(y1, ty1);
    float cx2 = fmaxf(x2, tx2), cy2 = fmaxf(y2, ty2);
    float cw = fmaxf(cx2 - cx1, 0.0f), ch = fmaxf(cy2 - cy1, 0.0f);
    float ac = cw * ch;
    float g = iou - (ac - uni) / ac;
    ok = (-g > -0.1f);                       // all(-g > bbox_thresh)
  }
  keep = keep && __all(ok);

  if (lane == 0) {
    labels[wid]   = arg;
    mask_out[wid] = keep ? 1.0f : 0.0f;
  }
}

// ---------------------------------------------------------------------------
// K12: merged (k1 | k2) — disjoint blockIdx ranges, one graph node.
// K2 part: elementwise class cost over current-model logits (float4 stream).
// ---------------------------------------------------------------------------
__global__ __launch_bounds__(256) void k12(
    const float* __restrict__ logits_base,
    const float4* __restrict__ boxes_base,
    const float4* __restrict__ targets,
    int* __restrict__ labels,
    float* __restrict__ mask_out,
    const f32x4* __restrict__ lg4,
    f32x4* __restrict__ cc4) {
  int tid = threadIdx.x;
  if (blockIdx.x < K1_BLOCKS) {
    int wid = (blockIdx.x * 256 + tid) >> 6;
    mask_label_body(wid, tid & 63, logits_base, boxes_base, targets,
                    labels, mask_out);
  } else {
    int i = (blockIdx.x - K1_BLOCKS) * 256 + tid;
    if (i < N4) {
      f32x4 v = __builtin_nontemporal_load(lg4 + i);
      f32x4 o;
      o.x = class_cost(v.x);
      o.y = class_cost(v.y);
      o.z = class_cost(v.z);
      o.w = class_cost(v.w);
      cc4[i] = o;
    }
  }
}

// ---------------------------------------------------------------------------
// K3: cost matrix. Block = (b, 12 q-rows) x all 900 qb; thread t<225 owns 4
// consecutive qb -> one nontemporal float4 store per row. Column state cut to
// 8 regs/col; LDS gather pointer precomputed per column so each gather is a
// bare ds_read with immediate offset. launch_bounds(256,4): <=128 VGPR,
// 16 waves/CU.
// ---------------------------------------------------------------------------
__global__ __launch_bounds__(256, 4) void k3_cost(
    const float* __restrict__ cc_all,
    const float4* __restrict__ pred_boxes,
    const float4* __restrict__ boxes_base,
    const int* __restrict__ labels,
    const float* __restrict__ mask_in,
    float* __restrict__ Cout) {
  __shared__ float  s_cc[QT * NC];   // 1092 floats (4.4 KB)
  __shared__ float4 s_e[QT];         // px1, py1, px2, py2
  __shared__ float4 s_m[QT];         // psx=px1+px2, psy, pw, ph
  __shared__ float  s_pa[QT];        // row area

  int b   = blockIdx.x / (Q / QT);
  int q0  = (blockIdx.x % (Q / QT)) * QT;
  int tid = threadIdx.x;

  // stage class costs: vector copy (273 aligned float4, single-use -> nt)
  const f32x4* ccs = reinterpret_cast<const f32x4*>(
      cc_all + ((size_t)(b * Q + q0)) * NC);
  f32x4* sc4 = reinterpret_cast<f32x4*>(s_cc);
  for (int i = tid; i < QT * NC / 4; i += 256)
    sc4[i] = __builtin_nontemporal_load(ccs + i);

  if (tid < QT) {
    float4 pb = pred_boxes[b * Q + q0 + tid];
    float px1 = pb.x - 0.5f * pb.z, py1 = pb.y - 0.5f * pb.w;
    float px2 = pb.x + 0.5f * pb.z, py2 = pb.y + 0.5f * pb.w;
    s_e[tid]  = make_float4(px1, py1, px2, py2);
    s_m[tid]  = make_float4(px1 + px2, py1 + py2, pb.z, pb.w);
    s_pa[tid] = (px2 - px1) * (py2 - py1);
  }

  // per-thread qb-side state: 4 consecutive columns, 8 regs each
  bool active = (tid < Q / 4);  // 225
  float x1b[4], y1b[4], x2b[4], y2b[4], wb[4], hb[4], c2big[4];
  const float* pk[4];
  int jbase = b * Q + 4 * tid;
  if (active) {
    int4 lbv = *reinterpret_cast<const int4*>(labels + jbase);
    float4 mkv = *reinterpret_cast<const float4*>(mask_in + jbase);
    pk[0] = s_cc + lbv.x; pk[1] = s_cc + lbv.y;
    pk[2] = s_cc + lbv.z; pk[3] = s_cc + lbv.w;
    c2big[0] = 2.0f + (mkv.x != 0.0f ? 0.0f : BIG_);
    c2big[1] = 2.0f + (mkv.y != 0.0f ? 0.0f : BIG_);
    c2big[2] = 2.0f + (mkv.z != 0.0f ? 0.0f : BIG_);
    c2big[3] = 2.0f + (mkv.w != 0.0f ? 0.0f : BIG_);
#pragma unroll
    for (int k = 0; k < 4; ++k) {
      float4 bb = boxes_base[jbase + k];
      x1b[k] = bb.x - 0.5f * bb.z; y1b[k] = bb.y - 0.5f * bb.w;
      x2b[k] = bb.x + 0.5f * bb.z; y2b[k] = bb.y + 0.5f * bb.w;
      wb[k]  = bb.z; hb[k] = bb.w;
    }
  }
  __syncthreads();

  if (active) {
    size_t rowbase = ((size_t)(b * Q + q0)) * Q + 4 * tid;
#pragma unroll
    for (int qi = 0; qi < QT; ++qi, rowbase += Q) {
      float4 pe = s_e[qi];
      float4 pm = s_m[qi];
      float  pa = s_pa[qi];
      float res[4];
#pragma unroll
      for (int k = 0; k < 4; ++k) {
        float cls = pk[k][qi * NC];  // ds_read, immediate offset qi*364
        // L1 in corner-sum form: |2dcx| = |psx - (x1b+x2b)|, |dw| = |pw - wb|
        float dx = pm.x - (x1b[k] + x2b[k]);
        float dy = pm.y - (y1b[k] + y2b[k]);
        float dw = pm.z - wb[k];
        float dh = pm.w - hb[k];
        float l1 = fmaf(0.5f, fabsf(dx) + fabsf(dy), fabsf(dw) + fabsf(dh));
        // intersection span (unclipped)
        float mwx = fminf(pe.z, x2b[k]) - fmaxf(pe.x, x1b[k]);
        float mwy = fminf(pe.w, y2b[k]) - fmaxf(pe.y, y1b[k]);
        float inter = fmaxf(mwx, 0.0f) * fmaxf(mwy, 0.0f);
        float uni = fmaf(wb[k], hb[k], pa) - inter;
        // enclosing box via identity: cw = (pw + wb) - mwx
        float cw = (pm.z + wb[k]) - mwx;
        float ch = (pm.w + hb[k]) - mwy;
        float acl = cw * ch;
        // t = iou + uni/acl = (inter*acl + uni^2) / (uni*acl)
        float r = __builtin_amdgcn_rcpf(uni * acl);
        float t = fmaf(inter, acl, uni * uni) * r;
        res[k] = fmaf(-2.0f, t, fmaf(5.0f, l1, fmaf(2.0f, cls, c2big[k])));
      }
      f32x4 out4 = {res[0], res[1], res[2], res[3]};
      __builtin_nontemporal_store(out4,
          reinterpret_cast<f32x4*>(Cout + rowbase));
    }
  }
}

extern "C" void kernel_launch(void* const* d_in, const int* in_sizes, int n_in,
                              void* d_out, int out_size, void* d_ws, size_t ws_size,
                              hipStream_t stream) {
  const float*  pred_logits      = (const float*)d_in[0];
  const float4* pred_boxes       = (const float4*)d_in[1];
  const float*  pred_logits_base = (const float*)d_in[2];
  const float4* pred_boxes_base  = (const float4*)d_in[3];
  const float4* targets          = (const float4*)d_in[4];

  float* out      = (float*)d_out;
  float* mask_out = out + (size_t)B * Q * Q;  // output 1, after C

  int*   labels = (int*)d_ws;                      // 28800 ints
  float* cc     = (float*)((char*)d_ws + 131072);  // 2.62M floats

  k12<<<K1_BLOCKS + K2_BLOCKS, 256, 0, stream>>>(
      pred_logits_base, pred_boxes_base, targets, labels, mask_out,
      (const f32x4*)pred_logits, (f32x4*)cc);

  k3_cost<<<B * (Q / QT), 256, 0, stream>>>(
      cc, pred_boxes, pred_boxes_base, labels, mask_out, out);
}